// Round 10
// baseline (286.065 us; speedup 1.0000x reference)
//
#include <hip/hip_runtime.h>
#include <math.h>

#define ALPHA 0.466f
#define T_FRAMES 200
#define HOPW 120
#define NSAMP 24000
#define M1 40
#define HID 256
#define CONDW 192

// time-chunking: NCHUNK chunks of CHUNKF output frames, WARMF warm-up frames
// from zero state. Block = 128 threads = 2 waves: wave0 = periodic filter b,
// wave1 = aperiodic filter 4+b (same chunk) -> P+A combine happens in-block,
// no separate combine kernel, no y2g HBM round-trip. 400 blocks -> <=1
// wave/SIMD still holds.
#define NCHUNK 100
#define CHUNKF 2
#define WARMF 4
#define SERF (WARMF + CHUNKF)   // 6 frames serial per chunk

#define F8 8                     // frames per embed block
#define EMB_BLOCKS (4 * T_FRAMES / F8)       // 100
#define BPF ((NSAMP + 255) / 256)            // exc blocks per filter (94)

// ---------------------------------------------------------------------------
// Kernel P: embed (blocks 0..99) U exc (blocks 100..851) in ONE dispatch.
// Round-9 evidence: ~25-35us per kernel launch in this harness -> fuse.
// ---------------------------------------------------------------------------
__global__ __launch_bounds__(256) void prep_kernel(
    const float* __restrict__ mceps, const float* __restrict__ apdcs,
    const float* __restrict__ f0s, const float* __restrict__ noise,
    const float* __restrict__ Wm, const float* __restrict__ bm,
    const float* __restrict__ Wa, const float* __restrict__ ba,
    const float* __restrict__ Wf, const float* __restrict__ bf,
    const float* __restrict__ Wpa, const float* __restrict__ bpa,
    const float* __restrict__ Wpp, const float* __restrict__ bpp,
    const float* __restrict__ Wrp, const float* __restrict__ brp,
    const float* __restrict__ Wra, const float* __restrict__ bra,
    const float* __restrict__ Wap,
    float* __restrict__ bcoef, float* __restrict__ exc)
{
    const int tid = threadIdx.x;

    if (blockIdx.x >= EMB_BLOCKS) {
        // =================== excitation path ===================
        const int xb = blockIdx.x - EMB_BLOCKS;
        const int ff = xb / BPF;
        const int n = (xb % BPF) * 256 + tid;

        if (ff >= 4) {
            if (n < NSAMP) exc[ff * NSAMP + n] = 0.5f * noise[(ff - 4) * NSAMP + n];
            return;
        }

        __shared__ double s_base[T_FRAMES];
        __shared__ double s_step[T_FRAMES];
        __shared__ float  s_amp[T_FRAMES];

        if (tid < 64) {
            const int L = tid;
            double st[4], loc[4];
            float am[4];
            double s = 0.0;
            #pragma unroll
            for (int j = 0; j < 4; ++j) {
                int ft = L * 4 + j;
                if (ft < T_FRAMES) {
                    double fv = exp((double)f0s[ff * T_FRAMES + ft] * 0.25 + 5.0);
                    st[j] = fv / 24000.0;
                    am[j] = (float)(0.5 * sqrt(24000.0 / fmax(fv, 1.0)));
                } else { st[j] = 0.0; am[j] = 0.f; }
                loc[j] = s;
                s += st[j];
            }
            double tot = s;
            #pragma unroll
            for (int off = 1; off < 64; off <<= 1) {
                double v = __shfl_up(s, off, 64);
                if (L >= off) s += v;
            }
            double excl = s - tot;
            #pragma unroll
            for (int j = 0; j < 4; ++j) {
                int ft = L * 4 + j;
                if (ft < T_FRAMES) {
                    s_base[ft] = 120.0 * (excl + loc[j]);
                    s_step[ft] = st[j];
                    s_amp[ft]  = am[j];
                }
            }
        }
        __syncthreads();

        if (n < NSAMP) {
            int ft = n / HOPW, k = n - ft * HOPW;
            double st = s_step[ft], bs = s_base[ft];
            double ph  = bs + (double)(k + 1) * st;
            double php = bs + (double)k * st;
            exc[ff * NSAMP + n] = (floor(ph) > floor(php)) ? s_amp[ft] : 0.0f;
        }
        return;
    }

    // =================== embed path (blocks 0..99) ===================
    __shared__ float s_mc[F8][M1];
    __shared__ float s_ap[F8][5];
    __shared__ float s_f0[F8];
    __shared__ float s_h[F8][HID];
    __shared__ float s_ca[F8][CONDW];
    __shared__ float s_cp[F8][CONDW];
    __shared__ float s_mcp[F8][M1];
    __shared__ float s_mca[F8][M1];

    const int R0 = blockIdx.x * F8;

    for (int j = tid; j < F8 * M1; j += 256) s_mc[j / M1][j % M1] = mceps[R0 * M1 + j];
    if (tid < F8 * 5) s_ap[tid / 5][tid % 5] = apdcs[R0 * 5 + tid];
    if (tid < F8)     s_f0[tid] = f0s[R0 + tid];
    __syncthreads();

    {
        float acc[F8];
        const float bias = bm[tid] + ba[tid] + bf[tid];
        #pragma unroll
        for (int r = 0; r < F8; ++r) acc[r] = bias;
        for (int k = 0; k < M1; ++k) {
            float w = Wm[k * HID + tid];
            #pragma unroll
            for (int r = 0; r < F8; ++r) acc[r] = fmaf(s_mc[r][k], w, acc[r]);
        }
        #pragma unroll
        for (int k = 0; k < 5; ++k) {
            float w = Wa[k * HID + tid];
            #pragma unroll
            for (int r = 0; r < F8; ++r) acc[r] = fmaf(s_ap[r][k], w, acc[r]);
        }
        float wf = Wf[tid];
        #pragma unroll
        for (int r = 0; r < F8; ++r) s_h[r][tid] = fmaf(s_f0[r], wf, acc[r]);
    }
    __syncthreads();

    if (tid < CONDW) {
        float aA[F8], aP[F8];
        #pragma unroll
        for (int r = 0; r < F8; ++r) { aA[r] = bpa[tid]; aP[r] = bpp[tid]; }
        for (int k = 0; k < HID; k += 4) {
            float4 h4[F8];
            #pragma unroll
            for (int r = 0; r < F8; ++r) h4[r] = *(const float4*)&s_h[r][k];
            #pragma unroll
            for (int kk = 0; kk < 4; ++kk) {
                float wa = Wpa[(k + kk) * CONDW + tid];
                float wp = Wpp[(k + kk) * CONDW + tid];
                #pragma unroll
                for (int r = 0; r < F8; ++r) {
                    float hv = (&h4[r].x)[kk];
                    aA[r] = fmaf(hv, wa, aA[r]);
                    aP[r] = fmaf(hv, wp, aP[r]);
                }
            }
        }
        #pragma unroll
        for (int r = 0; r < F8; ++r) { s_ca[r][tid] = aA[r]; s_cp[r][tid] = aP[r]; }
    }
    __syncthreads();

    if (tid < M1) {
        const int u = tid;
        float acc[F8];
        #pragma unroll
        for (int r = 0; r < F8; ++r) acc[r] = brp[u];
        for (int k = 0; k < CONDW; k += 4) {
            float4 c4[F8];
            #pragma unroll
            for (int r = 0; r < F8; ++r) c4[r] = *(const float4*)&s_cp[r][k];
            #pragma unroll
            for (int kk = 0; kk < 4; ++kk) {
                float w = Wrp[(k + kk) * M1 + u];
                #pragma unroll
                for (int r = 0; r < F8; ++r) acc[r] = fmaf((&c4[r].x)[kk], w, acc[r]);
            }
        }
        #pragma unroll
        for (int r = 0; r < F8; ++r)
            s_mcp[r][u] = s_mc[r][u] + 0.1f * tanhf(acc[r]);
    } else if (tid >= 64 && tid < 64 + M1) {
        const int u = tid - 64;
        float acc[F8];
        #pragma unroll
        for (int r = 0; r < F8; ++r) acc[r] = bra[u];
        for (int k = 0; k < CONDW; k += 4) {
            float4 c4[F8];
            #pragma unroll
            for (int r = 0; r < F8; ++r) c4[r] = *(const float4*)&s_ca[r][k];
            #pragma unroll
            for (int kk = 0; kk < 4; ++kk) {
                float w = Wra[(k + kk) * M1 + u];
                #pragma unroll
                for (int r = 0; r < F8; ++r) acc[r] = fmaf((&c4[r].x)[kk], w, acc[r]);
            }
        }
        #pragma unroll
        for (int r = 0; r < F8; ++r) {
            float aw = 0.f;
            #pragma unroll
            for (int j = 0; j < 5; ++j) aw = fmaf(s_ap[r][j], Wap[j * M1 + u], aw);
            s_mca[r][u] = s_mc[r][u] + 0.1f * tanhf(acc[r]) + aw;
        }
    }
    __syncthreads();

    if (tid < 16) {
        const int r = tid >> 1, path = tid & 1;
        const int R = R0 + r;
        const int batch = R / T_FRAMES, t = R - batch * T_FRAMES;
        const float* src = path ? s_mca[r] : s_mcp[r];
        float* dst = bcoef + ((path * 4 + batch) * T_FRAMES + t) * M1;
        float prev = src[M1 - 1];
        dst[M1 - 1] = prev;
        for (int m = M1 - 2; m >= 0; --m) {
            prev = src[m] - ALPHA * prev;
            dst[m] = prev;
        }
    }
}

// ---------------------------------------------------------------------------
// DPP helpers. row_shr:N = 0x110|N; row_bcast15 = 0x142.
// ---------------------------------------------------------------------------
template <int CTRL>
__device__ __forceinline__ float rshr(float x) {
    return __int_as_float(
        __builtin_amdgcn_mov_dpp(__float_as_int(x), CTRL, 0xF, 0xF, true));
}
__device__ __forceinline__ float rlane(float x, int l) {
    return __int_as_float(__builtin_amdgcn_readlane(__float_as_int(x), l));
}

// ---------------------------------------------------------------------------
// One frame of the lane-parallel MLSA scan (identical math to round 9).
// OUT frames: lane0 stashes y2 into the per-wave LDS buffer (combine done
// by the block after the frame).
// ---------------------------------------------------------------------------
template <bool OUT>
__device__ __forceinline__ void run_frame(
    const float* __restrict__ sx, float AB,
    float BP1, float BP2, float BP3, float BP4,
    float Ba, float Bb, float Bc, float K, float IPw, int i16, int row,
    bool lane0,
    float& E0, float& E1, float& E2, float& dlp, float& xin,
    float& m1, float& m2, float& m3, float& m4, float& w0,
    float* __restrict__ ybw)
{
    const float A = ALPHA;
    const float AA = 1.0f - A * A;
    const float A2 = A * A;
    const float R1 = -(A * A * A);
    const float R2 = R1 * R1;
    const float R4 = R2 * R2;
    const float R8 = R4 * R4;

    float xc = sx[0];
    #pragma unroll 8
    for (int k = 0; k < HOPW; ++k) {
        float xn = sx[k + 1];
        float x = xc;                                  // G pre-folded

        // stage 1 (SPTK mlsadf1), b1-rescaled, identical in all 64 lanes
        float na0 = AA * w0 + A * m1;
        float na1 = AB * m1 + A * m2;
        float na2 = AB * m2 + A * m3;
        float na3 = AB * m3 + A * m4;
        float v10 = na0 * BP1, v11 = na1 * BP2, v12 = na2 * BP3, v13 = na3 * BP4;
        float x1 = x + ((v10 - v11) + (v12 - v13));
        float y1 = ((v10 + v11) + (v12 + v13)) + x1;
        m1 = na0; m2 = na1; m3 = na2; m4 = na3; w0 = x1;

        // stage 2: blocked affine scan over the order recurrence
        float pE2 = rshr<0x111>(E2);
        float ca = fmaf(A, E0, (i16 == 0) ? dlp : pE2);
        float cb = fmaf(A, E1, E0);
        float cc = fmaf(A, E2, E1);
        float ua = ca;
        float ub = fmaf(-A, ua, cb);
        float uc = fmaf(-A, ub, cc);
        float X = uc;
        X = fmaf(R1, rshr<0x111>(X), X);
        X = fmaf(R2, rshr<0x112>(X), X);
        X = fmaf(R4, rshr<0x114>(X), X);
        X = fmaf(R8, rshr<0x118>(X), X);
        float dl = fmaf(AA, xin, A * dlp);
        float Xt = fmaf(K, dl, X);                    // true tt_{3i+2}
        float Si = rshr<0x111>(Xt);
        Si = (i16 == 0) ? dl : Si;                    // true tt_{3i-1}
        float ta = fmaf(-A, Si, ua);                  // tt_{3i}
        float tb = fmaf(A2, Si, ub);                  // tt_{3i+1}

        // P-weighted fy partial + row prefix-sum -> row totals ARE v2_r
        float fp = ta * Ba;
        fp = fmaf(tb, Bb, fp);
        fp = fmaf(Xt, Bc, fp);
        float S = fp;
        S += rshr<0x111>(S);
        S += rshr<0x112>(S);
        S += rshr<0x114>(S);
        S += rshr<0x118>(S);

        // xin for rows 1-3: previous row's total * (1/P_row), one DPP
        float xprev = rshr<0x142>(S) * IPw;

        // glue
        float v20 = rlane(S, 15);
        float v21 = rlane(S, 31);
        float v22 = rlane(S, 47);
        float v23 = rlane(S, 63);
        float e = v20 + v22, o = v21 + v23;
        float x2 = y1 + (e - o);
        if (OUT) {
            float y2 = (e + o) + x2;
            if (lane0) ybw[k] = y2;                   // per-wave stash
        }

        // next-sample inputs
        xin = (row == 0) ? x2 : xprev;
        E0 = ta; E1 = tb; E2 = Xt;
        dlp = dl;
        xc = xn;
    }
}

// ---------------------------------------------------------------------------
// Kernel D: MLSA scan, paired waves. Block = (chunk, batch b): wave0 runs
// periodic filter b, wave1 runs aperiodic filter 4+b; out frames combine
// in-block and store out = y_p + y_a directly.
// ---------------------------------------------------------------------------
__global__ __launch_bounds__(128) void mlsa_kernel(
    const float* __restrict__ bcoef, const float* __restrict__ exc,
    float* __restrict__ out)
{
    __shared__ float sexc[2][HOPW + 2];
    __shared__ float ybuf[2][HOPW];

    const int tid = threadIdx.x;
    const int w = tid >> 6;              // wave within block
    const int t64 = tid & 63;
    const int i16 = t64 & 15;
    const int row = t64 >> 4;
    const int chunk = blockIdx.x >> 2;
    const int b = blockIdx.x & 3;
    const int f = b + 4 * w;
    const bool lane0 = (t64 == 0);

    const float P1 = 0.4999273f, P2 = 0.1067005f, P3 = 0.00956526f, P4 = 0.0003041358f;
    const float Pw  = (row == 0) ? P1 : (row == 1) ? P2 : (row == 2) ? P3 : P4;
    const float IPw = (row == 1) ? (1.f / P1) : (row == 2) ? (1.f / P2) : (1.f / P3);

    const float R1 = -(ALPHA * ALPHA * ALPHA);
    float K = R1;
    for (int j = 0; j < i16; ++j) K *= R1;

    float E0 = 0.f, E1 = 0.f, E2 = 0.f;
    float dlp = 0.f, xin = 0.f;
    float m1 = 0.f, m2 = 0.f, m3 = 0.f, m4 = 0.f, w0 = 0.f;

    const int outF0 = chunk * CHUNKF;

    #pragma unroll 1
    for (int i = 0; i < SERF; ++i) {
        const int ftA = outF0 - WARMF + i;

        const int ftc = (ftA < 0) ? 0 : ftA;
        const float* bp = bcoef + (f * T_FRAMES + ftc) * M1;
        const float b1 = bp[1];
        const float G  = expf(bp[0]);
        const float AA = 1.0f - ALPHA * ALPHA;
        const float AB = AA * b1;
        const float BP1 = b1 * P1, BP2 = b1 * P2, BP3 = b1 * P3, BP4 = b1 * P4;

        // stage own wave's excitation, pre-scaled by G (per-wave buffer; no
        // cross-wave dependency -> no barrier needed here)
        for (int j = t64; j < HOPW; j += 64)
            sexc[w][j] = (ftA >= 0) ? exc[f * NSAMP + ftA * HOPW + j] * G : 0.f;
        if (lane0) sexc[w][HOPW] = 0.f;

        const int ja = 3 * i16 + 2;
        const float Ba = ((i16 <= 12) ? bp[ja]     : 0.f) * Pw;
        const float Bb = ((i16 <= 12) ? bp[ja + 1] : 0.f) * Pw;
        const float Bc = ((i16 <= 11) ? bp[ja + 2] : 0.f) * Pw;

        if (i >= WARMF) {
            run_frame<true>(sexc[w], AB, BP1, BP2, BP3, BP4, Ba, Bb, Bc, K, IPw,
                            i16, row, lane0, E0, E1, E2, dlp, xin,
                            m1, m2, m3, m4, w0, ybuf[w]);
            __syncthreads();                          // both waves' ybuf ready
            if (tid < HOPW)
                out[b * NSAMP + ftA * HOPW + tid] = ybuf[0][tid] + ybuf[1][tid];
            __syncthreads();                          // protect ybuf reuse
        } else {
            run_frame<false>(sexc[w], AB, BP1, BP2, BP3, BP4, Ba, Bb, Bc, K, IPw,
                             i16, row, lane0, E0, E1, E2, dlp, xin,
                             m1, m2, m3, m4, w0, ybuf[w]);
        }
    }
}

// ---------------------------------------------------------------------------
extern "C" void kernel_launch(void* const* d_in, const int* in_sizes, int n_in,
                              void* d_out, int out_size, void* d_ws, size_t ws_size,
                              hipStream_t stream) {
    const float* mceps = (const float*)d_in[0];
    const float* apdcs = (const float*)d_in[1];
    const float* f0s   = (const float*)d_in[2];
    const float* noise = (const float*)d_in[3];
    const float* Wm  = (const float*)d_in[4];
    const float* bm  = (const float*)d_in[5];
    const float* Wa  = (const float*)d_in[6];
    const float* ba  = (const float*)d_in[7];
    const float* Wf  = (const float*)d_in[8];
    const float* bf  = (const float*)d_in[9];
    const float* Wpa = (const float*)d_in[10];
    const float* bpa = (const float*)d_in[11];
    const float* Wpp = (const float*)d_in[12];
    const float* bpp = (const float*)d_in[13];
    const float* Wrp = (const float*)d_in[14];
    const float* brp = (const float*)d_in[15];
    const float* Wra = (const float*)d_in[16];
    const float* bra = (const float*)d_in[17];
    const float* Wap = (const float*)d_in[18];
    float* out = (float*)d_out;

    char* ws = (char*)d_ws;
    float* bcoef = (float*)(ws + 0);           // 256000 B
    float* exc   = (float*)(ws + 256000);      // 768000 B

    prep_kernel<<<dim3(EMB_BLOCKS + 8 * BPF), dim3(256), 0, stream>>>(
        mceps, apdcs, f0s, noise, Wm, bm, Wa, ba, Wf, bf,
        Wpa, bpa, Wpp, bpp, Wrp, brp, Wra, bra, Wap, bcoef, exc);

    mlsa_kernel<<<dim3(NCHUNK * 4), dim3(128), 0, stream>>>(bcoef, exc, out);
}

// Round 11
// 230.158 us; speedup vs baseline: 1.2429x; 1.2429x over previous
//
#include <hip/hip_runtime.h>
#include <math.h>

#define ALPHA 0.466f
#define T_FRAMES 200
#define HOPW 120
#define NSAMP 24000
#define M1 40
#define HID 256
#define CONDW 192

// time-chunking: NCHUNK chunks of CHUNKF output frames, WARMF warm-up frames
// from zero state. ONE WAVE PER BLOCK (round-10 lesson: 2-wave blocks get
// co-scheduled on one SIMD -> 2x issue time). 100*8 = 800 blocks <= 1024 SIMDs.
#define NCHUNK 100
#define CHUNKF 2
#define WARMF 3
#define SERF (WARMF + CHUNKF)   // 5 frames serial per chunk

#define F8 8                     // frames per embed block
#define EMB_BLOCKS (4 * T_FRAMES / F8)       // 100
#define BPF ((NSAMP + 255) / 256)            // exc blocks per filter (94)

typedef float v2f __attribute__((ext_vector_type(2)));

// ---------------------------------------------------------------------------
// Kernel P: embed (blocks 0..99) U exc (blocks 100..851) in ONE dispatch.
// ---------------------------------------------------------------------------
__global__ __launch_bounds__(256) void prep_kernel(
    const float* __restrict__ mceps, const float* __restrict__ apdcs,
    const float* __restrict__ f0s, const float* __restrict__ noise,
    const float* __restrict__ Wm, const float* __restrict__ bm,
    const float* __restrict__ Wa, const float* __restrict__ ba,
    const float* __restrict__ Wf, const float* __restrict__ bf,
    const float* __restrict__ Wpa, const float* __restrict__ bpa,
    const float* __restrict__ Wpp, const float* __restrict__ bpp,
    const float* __restrict__ Wrp, const float* __restrict__ brp,
    const float* __restrict__ Wra, const float* __restrict__ bra,
    const float* __restrict__ Wap,
    float* __restrict__ bcoef, float* __restrict__ exc)
{
    const int tid = threadIdx.x;

    if (blockIdx.x >= EMB_BLOCKS) {
        // =================== excitation path ===================
        const int xb = blockIdx.x - EMB_BLOCKS;
        const int ff = xb / BPF;
        const int n = (xb % BPF) * 256 + tid;

        if (ff >= 4) {
            if (n < NSAMP) exc[ff * NSAMP + n] = 0.5f * noise[(ff - 4) * NSAMP + n];
            return;
        }

        __shared__ double s_base[T_FRAMES];
        __shared__ double s_step[T_FRAMES];
        __shared__ float  s_amp[T_FRAMES];

        if (tid < 64) {
            const int L = tid;
            double st[4], loc[4];
            float am[4];
            double s = 0.0;
            #pragma unroll
            for (int j = 0; j < 4; ++j) {
                int ft = L * 4 + j;
                if (ft < T_FRAMES) {
                    double fv = exp((double)f0s[ff * T_FRAMES + ft] * 0.25 + 5.0);
                    st[j] = fv / 24000.0;
                    am[j] = (float)(0.5 * sqrt(24000.0 / fmax(fv, 1.0)));
                } else { st[j] = 0.0; am[j] = 0.f; }
                loc[j] = s;
                s += st[j];
            }
            double tot = s;
            #pragma unroll
            for (int off = 1; off < 64; off <<= 1) {
                double v = __shfl_up(s, off, 64);
                if (L >= off) s += v;
            }
            double excl = s - tot;
            #pragma unroll
            for (int j = 0; j < 4; ++j) {
                int ft = L * 4 + j;
                if (ft < T_FRAMES) {
                    s_base[ft] = 120.0 * (excl + loc[j]);
                    s_step[ft] = st[j];
                    s_amp[ft]  = am[j];
                }
            }
        }
        __syncthreads();

        if (n < NSAMP) {
            int ft = n / HOPW, k = n - ft * HOPW;
            double st = s_step[ft], bs = s_base[ft];
            double ph  = bs + (double)(k + 1) * st;
            double php = bs + (double)k * st;
            exc[ff * NSAMP + n] = (floor(ph) > floor(php)) ? s_amp[ft] : 0.0f;
        }
        return;
    }

    // =================== embed path (blocks 0..99) ===================
    __shared__ float s_mc[F8][M1];
    __shared__ float s_ap[F8][5];
    __shared__ float s_f0[F8];
    __shared__ float s_h[F8][HID];
    __shared__ float s_ca[F8][CONDW];
    __shared__ float s_cp[F8][CONDW];
    __shared__ float s_mcp[F8][M1];
    __shared__ float s_mca[F8][M1];

    const int R0 = blockIdx.x * F8;

    for (int j = tid; j < F8 * M1; j += 256) s_mc[j / M1][j % M1] = mceps[R0 * M1 + j];
    if (tid < F8 * 5) s_ap[tid / 5][tid % 5] = apdcs[R0 * 5 + tid];
    if (tid < F8)     s_f0[tid] = f0s[R0 + tid];
    __syncthreads();

    {
        float acc[F8];
        const float bias = bm[tid] + ba[tid] + bf[tid];
        #pragma unroll
        for (int r = 0; r < F8; ++r) acc[r] = bias;
        for (int k = 0; k < M1; ++k) {
            float w = Wm[k * HID + tid];
            #pragma unroll
            for (int r = 0; r < F8; ++r) acc[r] = fmaf(s_mc[r][k], w, acc[r]);
        }
        #pragma unroll
        for (int k = 0; k < 5; ++k) {
            float w = Wa[k * HID + tid];
            #pragma unroll
            for (int r = 0; r < F8; ++r) acc[r] = fmaf(s_ap[r][k], w, acc[r]);
        }
        float wf = Wf[tid];
        #pragma unroll
        for (int r = 0; r < F8; ++r) s_h[r][tid] = fmaf(s_f0[r], wf, acc[r]);
    }
    __syncthreads();

    if (tid < CONDW) {
        float aA[F8], aP[F8];
        #pragma unroll
        for (int r = 0; r < F8; ++r) { aA[r] = bpa[tid]; aP[r] = bpp[tid]; }
        for (int k = 0; k < HID; k += 4) {
            float4 h4[F8];
            #pragma unroll
            for (int r = 0; r < F8; ++r) h4[r] = *(const float4*)&s_h[r][k];
            #pragma unroll
            for (int kk = 0; kk < 4; ++kk) {
                float wa = Wpa[(k + kk) * CONDW + tid];
                float wp = Wpp[(k + kk) * CONDW + tid];
                #pragma unroll
                for (int r = 0; r < F8; ++r) {
                    float hv = (&h4[r].x)[kk];
                    aA[r] = fmaf(hv, wa, aA[r]);
                    aP[r] = fmaf(hv, wp, aP[r]);
                }
            }
        }
        #pragma unroll
        for (int r = 0; r < F8; ++r) { s_ca[r][tid] = aA[r]; s_cp[r][tid] = aP[r]; }
    }
    __syncthreads();

    if (tid < M1) {
        const int u = tid;
        float acc[F8];
        #pragma unroll
        for (int r = 0; r < F8; ++r) acc[r] = brp[u];
        for (int k = 0; k < CONDW; k += 4) {
            float4 c4[F8];
            #pragma unroll
            for (int r = 0; r < F8; ++r) c4[r] = *(const float4*)&s_cp[r][k];
            #pragma unroll
            for (int kk = 0; kk < 4; ++kk) {
                float w = Wrp[(k + kk) * M1 + u];
                #pragma unroll
                for (int r = 0; r < F8; ++r) acc[r] = fmaf((&c4[r].x)[kk], w, acc[r]);
            }
        }
        #pragma unroll
        for (int r = 0; r < F8; ++r)
            s_mcp[r][u] = s_mc[r][u] + 0.1f * tanhf(acc[r]);
    } else if (tid >= 64 && tid < 64 + M1) {
        const int u = tid - 64;
        float acc[F8];
        #pragma unroll
        for (int r = 0; r < F8; ++r) acc[r] = bra[u];
        for (int k = 0; k < CONDW; k += 4) {
            float4 c4[F8];
            #pragma unroll
            for (int r = 0; r < F8; ++r) c4[r] = *(const float4*)&s_ca[r][k];
            #pragma unroll
            for (int kk = 0; kk < 4; ++kk) {
                float w = Wra[(k + kk) * M1 + u];
                #pragma unroll
                for (int r = 0; r < F8; ++r) acc[r] = fmaf((&c4[r].x)[kk], w, acc[r]);
            }
        }
        #pragma unroll
        for (int r = 0; r < F8; ++r) {
            float aw = 0.f;
            #pragma unroll
            for (int j = 0; j < 5; ++j) aw = fmaf(s_ap[r][j], Wap[j * M1 + u], aw);
            s_mca[r][u] = s_mc[r][u] + 0.1f * tanhf(acc[r]) + aw;
        }
    }
    __syncthreads();

    if (tid < 16) {
        const int r = tid >> 1, path = tid & 1;
        const int R = R0 + r;
        const int batch = R / T_FRAMES, t = R - batch * T_FRAMES;
        const float* src = path ? s_mca[r] : s_mcp[r];
        float* dst = bcoef + ((path * 4 + batch) * T_FRAMES + t) * M1;
        float prev = src[M1 - 1];
        dst[M1 - 1] = prev;
        for (int m = M1 - 2; m >= 0; --m) {
            prev = src[m] - ALPHA * prev;
            dst[m] = prev;
        }
    }
}

// ---------------------------------------------------------------------------
// DPP helpers. row_shr:N = 0x110|N; row_bcast15 = 0x142.
// ---------------------------------------------------------------------------
template <int CTRL>
__device__ __forceinline__ float rshr(float x) {
    return __int_as_float(
        __builtin_amdgcn_mov_dpp(__float_as_int(x), CTRL, 0xF, 0xF, true));
}
__device__ __forceinline__ float rlane(float x, int l) {
    return __int_as_float(__builtin_amdgcn_readlane(__float_as_int(x), l));
}

// ---------------------------------------------------------------------------
// One frame of the lane-parallel MLSA scan.
// Stage 1 uses packed fp32 (v_pk_fma_f32): pairs (na0,na2)/(na1,na3) with
// stride-2 state PB=(m1,m3), PC=(m2,m4). The dl input constant AAP folds
// AA*(1/P_row) so the xin handoff is one cndmask + pk-style fma.
// ---------------------------------------------------------------------------
template <bool OUT>
__device__ __forceinline__ void run_frame(
    const float* __restrict__ sx,
    v2f Cv, v2f BP13, v2f BP24,
    float Ba, float Bb, float Bc, float K, float AAP, int i16, int row,
    float& E0, float& E1, float& E2, float& dlp, float& src,
    v2f& PB, v2f& PC, float& w0,
    float* __restrict__ yout)
{
    const float A = ALPHA;
    const float A2 = A * A;
    const float R1 = -(A * A * A);
    const float R2 = R1 * R1;
    const float R4 = R2 * R2;
    const float R8 = R4 * R4;

    float xc = sx[0];
    #pragma unroll 8
    for (int k = 0; k < HOPW; ++k) {
        float xn = sx[k + 1];
        float x = xc;                                  // G pre-folded

        // ---- stage 1 (SPTK mlsadf1), packed: pairs (na0,na2), (na1,na3) ----
        v2f PA; PA.x = w0; PA.y = PC.x;                // (w0, m2)
        v2f NA02 = __builtin_elementwise_fma(Cv, PA, A * PB);   // (na0,na2)
        v2f NA13 = __builtin_elementwise_fma((v2f)(Cv.y), PB, A * PC); // (na1,na3)
        v2f VA = NA02 * BP13;                          // (v10, v12)
        v2f VB = NA13 * BP24;                          // (v11, v13)
        v2f D = VA - VB;
        v2f Sm = VA + VB;
        float x1 = x + (D.x + D.y);
        float y1 = (Sm.x + Sm.y) + x1;
        PB = NA02; PC = NA13; w0 = x1;

        // ---- stage 2: blocked affine scan over the order recurrence ----
        float dl = fmaf(AAP, src, A * dlp);
        float pE2 = rshr<0x111>(E2);
        float ca = fmaf(A, E0, (i16 == 0) ? dlp : pE2);
        float cb = fmaf(A, E1, E0);
        float cc = fmaf(A, E2, E1);
        float ua = ca;
        float ub = fmaf(-A, ua, cb);
        float uc = fmaf(-A, ub, cc);
        float X = uc;
        X = fmaf(R1, rshr<0x111>(X), X);
        X = fmaf(R2, rshr<0x112>(X), X);
        X = fmaf(R4, rshr<0x114>(X), X);
        X = fmaf(R8, rshr<0x118>(X), X);
        float Xt = fmaf(K, dl, X);                    // true tt_{3i+2}
        float Si = rshr<0x111>(Xt);
        Si = (i16 == 0) ? dl : Si;                    // true tt_{3i-1}
        float ta = fmaf(-A, Si, ua);                  // tt_{3i}
        float tb = fmaf(A2, Si, ub);                  // tt_{3i+1}

        // P-weighted fy partial + row prefix-sum -> row totals ARE v2_r
        float fp = ta * Ba;
        fp = fmaf(tb, Bb, fp);
        fp = fmaf(Xt, Bc, fp);
        float S = fp;
        S += rshr<0x111>(S);
        S += rshr<0x112>(S);
        S += rshr<0x114>(S);
        S += rshr<0x118>(S);

        // glue: v2 totals; y2 = y1 + 2e exactly
        float v20 = rlane(S, 15);
        float v21 = rlane(S, 31);
        float v22 = rlane(S, 47);
        float v23 = rlane(S, 63);
        float e = v20 + v22, o = v21 + v23;
        float x2 = y1 + (e - o);
        if (OUT) {
            float y2 = fmaf(2.f, e, y1);
            yout[k] = y2;                             // all lanes, same value
        }

        // next-sample inputs (AAP folds 1/P_row at the dl use site)
        src = (row == 0) ? x2 : rshr<0x142>(S);
        E0 = ta; E1 = tb; E2 = Xt;
        dlp = dl;
        xc = xn;
    }
}

// ---------------------------------------------------------------------------
// Kernel D: MLSA synthesis scan (block = ONE wave = one (chunk, filter)).
// ---------------------------------------------------------------------------
__global__ __launch_bounds__(64) void mlsa_kernel(
    const float* __restrict__ bcoef, const float* __restrict__ exc,
    float* __restrict__ y2g)
{
    __shared__ float sexc[HOPW + 2];

    const int tid = threadIdx.x;
    const int i16 = tid & 15;
    const int row = tid >> 4;
    const int chunk = blockIdx.x >> 3;
    const int f = blockIdx.x & 7;

    const float P1 = 0.4999273f, P2 = 0.1067005f, P3 = 0.00956526f, P4 = 0.0003041358f;
    const float Pw  = (row == 0) ? P1 : (row == 1) ? P2 : (row == 2) ? P3 : P4;
    const float AAc = 1.0f - ALPHA * ALPHA;
    const float AAP = (row == 0) ? AAc
                    : (row == 1) ? (AAc / P1)
                    : (row == 2) ? (AAc / P2) : (AAc / P3);

    const float R1 = -(ALPHA * ALPHA * ALPHA);
    float K = R1;
    for (int j = 0; j < i16; ++j) K *= R1;

    float E0 = 0.f, E1 = 0.f, E2 = 0.f;
    float dlp = 0.f, src = 0.f;
    v2f PB = (v2f)(0.f), PC = (v2f)(0.f);
    float w0 = 0.f;

    const int outF0 = chunk * CHUNKF;

    #pragma unroll 1
    for (int i = 0; i < SERF; ++i) {
        const int ftA = outF0 - WARMF + i;

        const int ftc = (ftA < 0) ? 0 : ftA;
        const float* bp = bcoef + (f * T_FRAMES + ftc) * M1;
        const float b1 = bp[1];
        const float G  = expf(bp[0]);
        v2f Cv;   Cv.x = AAc;      Cv.y = AAc * b1;     // (AA, AB)
        v2f BP13; BP13.x = b1 * P1; BP13.y = b1 * P3;
        v2f BP24; BP24.x = b1 * P2; BP24.y = b1 * P4;

        // stage excitation, pre-scaled by G (single wave: no barrier needed)
        for (int j = tid; j < HOPW; j += 64)
            sexc[j] = (ftA >= 0) ? exc[f * NSAMP + ftA * HOPW + j] * G : 0.f;
        if (tid == 0) sexc[HOPW] = 0.f;

        const int ja = 3 * i16 + 2;
        const float Ba = ((i16 <= 12) ? bp[ja]     : 0.f) * Pw;
        const float Bb = ((i16 <= 12) ? bp[ja + 1] : 0.f) * Pw;
        const float Bc = ((i16 <= 11) ? bp[ja + 2] : 0.f) * Pw;
        float* yout = y2g + f * NSAMP + ftA * HOPW;

        if (i >= WARMF)
            run_frame<true>(sexc, Cv, BP13, BP24, Ba, Bb, Bc, K, AAP, i16, row,
                            E0, E1, E2, dlp, src, PB, PC, w0, yout);
        else
            run_frame<false>(sexc, Cv, BP13, BP24, Ba, Bb, Bc, K, AAP, i16, row,
                             E0, E1, E2, dlp, src, PB, PC, w0, yout);
    }
}

// ---------------------------------------------------------------------------
// Kernel E: out[b][n] = y2g[b][n] + y2g[4+b][n]
// ---------------------------------------------------------------------------
__global__ __launch_bounds__(256) void combine_kernel(
    const float* __restrict__ y2g, float* __restrict__ out)
{
    int i = blockIdx.x * 256 + threadIdx.x;
    if (i >= 4 * NSAMP) return;
    int b = i / NSAMP, n = i - b * NSAMP;
    out[i] = y2g[b * NSAMP + n] + y2g[(4 + b) * NSAMP + n];
}

// ---------------------------------------------------------------------------
extern "C" void kernel_launch(void* const* d_in, const int* in_sizes, int n_in,
                              void* d_out, int out_size, void* d_ws, size_t ws_size,
                              hipStream_t stream) {
    const float* mceps = (const float*)d_in[0];
    const float* apdcs = (const float*)d_in[1];
    const float* f0s   = (const float*)d_in[2];
    const float* noise = (const float*)d_in[3];
    const float* Wm  = (const float*)d_in[4];
    const float* bm  = (const float*)d_in[5];
    const float* Wa  = (const float*)d_in[6];
    const float* ba  = (const float*)d_in[7];
    const float* Wf  = (const float*)d_in[8];
    const float* bf  = (const float*)d_in[9];
    const float* Wpa = (const float*)d_in[10];
    const float* bpa = (const float*)d_in[11];
    const float* Wpp = (const float*)d_in[12];
    const float* bpp = (const float*)d_in[13];
    const float* Wrp = (const float*)d_in[14];
    const float* brp = (const float*)d_in[15];
    const float* Wra = (const float*)d_in[16];
    const float* bra = (const float*)d_in[17];
    const float* Wap = (const float*)d_in[18];
    float* out = (float*)d_out;

    char* ws = (char*)d_ws;
    float* bcoef = (float*)(ws + 0);           // 256000 B
    float* exc   = (float*)(ws + 256000);      // 768000 B
    float* y2g   = (float*)(ws + 1024000);     // 768000 B

    prep_kernel<<<dim3(EMB_BLOCKS + 8 * BPF), dim3(256), 0, stream>>>(
        mceps, apdcs, f0s, noise, Wm, bm, Wa, ba, Wf, bf,
        Wpa, bpa, Wpp, bpp, Wrp, brp, Wra, bra, Wap, bcoef, exc);

    mlsa_kernel<<<dim3(NCHUNK * 8), dim3(64), 0, stream>>>(bcoef, exc, y2g);

    combine_kernel<<<dim3((4 * NSAMP + 255) / 256), dim3(256), 0, stream>>>(
        y2g, out);
}

// Round 12
// 219.993 us; speedup vs baseline: 1.3003x; 1.0462x over previous
//
#include <hip/hip_runtime.h>
#include <math.h>

#define ALPHA 0.466f
#define T_FRAMES 200
#define HOPW 120
#define NSAMP 24000
#define M1 40
#define HID 256
#define CONDW 192

// time-chunking: NCHUNK chunks of CHUNKF output frames, WARMF warm-up frames
// from zero state. ONE WAVE PER BLOCK (r10: 2-wave blocks co-schedule on one
// SIMD -> 2x issue). 800 blocks <= 1024 SIMDs. WARMF=4 is the accuracy floor
// (r11: WARMF=3 -> absmax 0.25 vs 0.28 threshold; error grows ~8x/frame).
#define NCHUNK 100
#define CHUNKF 2
#define WARMF 4
#define SERF (WARMF + CHUNKF)   // 6 frames serial per chunk

#define F8 8                     // frames per embed block
#define EMB_BLOCKS (4 * T_FRAMES / F8)       // 100
#define BPF ((NSAMP + 255) / 256)            // exc blocks per filter (94)

// ---------------------------------------------------------------------------
// Kernel P: embed (blocks 0..99) U exc (blocks 100..851) in ONE dispatch.
// ---------------------------------------------------------------------------
__global__ __launch_bounds__(256) void prep_kernel(
    const float* __restrict__ mceps, const float* __restrict__ apdcs,
    const float* __restrict__ f0s, const float* __restrict__ noise,
    const float* __restrict__ Wm, const float* __restrict__ bm,
    const float* __restrict__ Wa, const float* __restrict__ ba,
    const float* __restrict__ Wf, const float* __restrict__ bf,
    const float* __restrict__ Wpa, const float* __restrict__ bpa,
    const float* __restrict__ Wpp, const float* __restrict__ bpp,
    const float* __restrict__ Wrp, const float* __restrict__ brp,
    const float* __restrict__ Wra, const float* __restrict__ bra,
    const float* __restrict__ Wap,
    float* __restrict__ bcoef, float* __restrict__ exc)
{
    const int tid = threadIdx.x;

    if (blockIdx.x >= EMB_BLOCKS) {
        // =================== excitation path ===================
        const int xb = blockIdx.x - EMB_BLOCKS;
        const int ff = xb / BPF;
        const int n = (xb % BPF) * 256 + tid;

        if (ff >= 4) {
            if (n < NSAMP) exc[ff * NSAMP + n] = 0.5f * noise[(ff - 4) * NSAMP + n];
            return;
        }

        __shared__ double s_base[T_FRAMES];
        __shared__ double s_step[T_FRAMES];
        __shared__ float  s_amp[T_FRAMES];

        if (tid < 64) {
            const int L = tid;
            double st[4], loc[4];
            float am[4];
            double s = 0.0;
            #pragma unroll
            for (int j = 0; j < 4; ++j) {
                int ft = L * 4 + j;
                if (ft < T_FRAMES) {
                    double fv = exp((double)f0s[ff * T_FRAMES + ft] * 0.25 + 5.0);
                    st[j] = fv / 24000.0;
                    am[j] = (float)(0.5 * sqrt(24000.0 / fmax(fv, 1.0)));
                } else { st[j] = 0.0; am[j] = 0.f; }
                loc[j] = s;
                s += st[j];
            }
            double tot = s;
            #pragma unroll
            for (int off = 1; off < 64; off <<= 1) {
                double v = __shfl_up(s, off, 64);
                if (L >= off) s += v;
            }
            double excl = s - tot;
            #pragma unroll
            for (int j = 0; j < 4; ++j) {
                int ft = L * 4 + j;
                if (ft < T_FRAMES) {
                    s_base[ft] = 120.0 * (excl + loc[j]);
                    s_step[ft] = st[j];
                    s_amp[ft]  = am[j];
                }
            }
        }
        __syncthreads();

        if (n < NSAMP) {
            int ft = n / HOPW, k = n - ft * HOPW;
            double st = s_step[ft], bs = s_base[ft];
            double ph  = bs + (double)(k + 1) * st;
            double php = bs + (double)k * st;
            exc[ff * NSAMP + n] = (floor(ph) > floor(php)) ? s_amp[ft] : 0.0f;
        }
        return;
    }

    // =================== embed path (blocks 0..99) ===================
    __shared__ float s_mc[F8][M1];
    __shared__ float s_ap[F8][5];
    __shared__ float s_f0[F8];
    __shared__ float s_h[F8][HID];
    __shared__ float s_ca[F8][CONDW];
    __shared__ float s_cp[F8][CONDW];
    __shared__ float s_mcp[F8][M1];
    __shared__ float s_mca[F8][M1];

    const int R0 = blockIdx.x * F8;

    for (int j = tid; j < F8 * M1; j += 256) s_mc[j / M1][j % M1] = mceps[R0 * M1 + j];
    if (tid < F8 * 5) s_ap[tid / 5][tid % 5] = apdcs[R0 * 5 + tid];
    if (tid < F8)     s_f0[tid] = f0s[R0 + tid];
    __syncthreads();

    {
        float acc[F8];
        const float bias = bm[tid] + ba[tid] + bf[tid];
        #pragma unroll
        for (int r = 0; r < F8; ++r) acc[r] = bias;
        for (int k = 0; k < M1; ++k) {
            float w = Wm[k * HID + tid];
            #pragma unroll
            for (int r = 0; r < F8; ++r) acc[r] = fmaf(s_mc[r][k], w, acc[r]);
        }
        #pragma unroll
        for (int k = 0; k < 5; ++k) {
            float w = Wa[k * HID + tid];
            #pragma unroll
            for (int r = 0; r < F8; ++r) acc[r] = fmaf(s_ap[r][k], w, acc[r]);
        }
        float wf = Wf[tid];
        #pragma unroll
        for (int r = 0; r < F8; ++r) s_h[r][tid] = fmaf(s_f0[r], wf, acc[r]);
    }
    __syncthreads();

    if (tid < CONDW) {
        float aA[F8], aP[F8];
        #pragma unroll
        for (int r = 0; r < F8; ++r) { aA[r] = bpa[tid]; aP[r] = bpp[tid]; }
        for (int k = 0; k < HID; k += 4) {
            float4 h4[F8];
            #pragma unroll
            for (int r = 0; r < F8; ++r) h4[r] = *(const float4*)&s_h[r][k];
            #pragma unroll
            for (int kk = 0; kk < 4; ++kk) {
                float wa = Wpa[(k + kk) * CONDW + tid];
                float wp = Wpp[(k + kk) * CONDW + tid];
                #pragma unroll
                for (int r = 0; r < F8; ++r) {
                    float hv = (&h4[r].x)[kk];
                    aA[r] = fmaf(hv, wa, aA[r]);
                    aP[r] = fmaf(hv, wp, aP[r]);
                }
            }
        }
        #pragma unroll
        for (int r = 0; r < F8; ++r) { s_ca[r][tid] = aA[r]; s_cp[r][tid] = aP[r]; }
    }
    __syncthreads();

    if (tid < M1) {
        const int u = tid;
        float acc[F8];
        #pragma unroll
        for (int r = 0; r < F8; ++r) acc[r] = brp[u];
        for (int k = 0; k < CONDW; k += 4) {
            float4 c4[F8];
            #pragma unroll
            for (int r = 0; r < F8; ++r) c4[r] = *(const float4*)&s_cp[r][k];
            #pragma unroll
            for (int kk = 0; kk < 4; ++kk) {
                float w = Wrp[(k + kk) * M1 + u];
                #pragma unroll
                for (int r = 0; r < F8; ++r) acc[r] = fmaf((&c4[r].x)[kk], w, acc[r]);
            }
        }
        #pragma unroll
        for (int r = 0; r < F8; ++r)
            s_mcp[r][u] = s_mc[r][u] + 0.1f * tanhf(acc[r]);
    } else if (tid >= 64 && tid < 64 + M1) {
        const int u = tid - 64;
        float acc[F8];
        #pragma unroll
        for (int r = 0; r < F8; ++r) acc[r] = bra[u];
        for (int k = 0; k < CONDW; k += 4) {
            float4 c4[F8];
            #pragma unroll
            for (int r = 0; r < F8; ++r) c4[r] = *(const float4*)&s_ca[r][k];
            #pragma unroll
            for (int kk = 0; kk < 4; ++kk) {
                float w = Wra[(k + kk) * M1 + u];
                #pragma unroll
                for (int r = 0; r < F8; ++r) acc[r] = fmaf((&c4[r].x)[kk], w, acc[r]);
            }
        }
        #pragma unroll
        for (int r = 0; r < F8; ++r) {
            float aw = 0.f;
            #pragma unroll
            for (int j = 0; j < 5; ++j) aw = fmaf(s_ap[r][j], Wap[j * M1 + u], aw);
            s_mca[r][u] = s_mc[r][u] + 0.1f * tanhf(acc[r]) + aw;
        }
    }
    __syncthreads();

    if (tid < 16) {
        const int r = tid >> 1, path = tid & 1;
        const int R = R0 + r;
        const int batch = R / T_FRAMES, t = R - batch * T_FRAMES;
        const float* src = path ? s_mca[r] : s_mcp[r];
        float* dst = bcoef + ((path * 4 + batch) * T_FRAMES + t) * M1;
        float prev = src[M1 - 1];
        dst[M1 - 1] = prev;
        for (int m = M1 - 2; m >= 0; --m) {
            prev = src[m] - ALPHA * prev;
            dst[m] = prev;
        }
    }
}

// ---------------------------------------------------------------------------
// DPP helpers. row_shr:N = 0x110|N; row_bcast15 = 0x142.
// ---------------------------------------------------------------------------
template <int CTRL>
__device__ __forceinline__ float rshr(float x) {
    return __int_as_float(
        __builtin_amdgcn_mov_dpp(__float_as_int(x), CTRL, 0xF, 0xF, true));
}
__device__ __forceinline__ float rlane(float x, int l) {
    return __int_as_float(__builtin_amdgcn_readlane(__float_as_int(x), l));
}

// ---------------------------------------------------------------------------
// One frame of the lane-parallel MLSA scan — EXACT round-9 math (proven
// 332 cyc/sample, absmax 0.031; r11's packed stage-1 regressed to 435).
// OUT frames stash y2 in LDS ybuf (all-lane store); atomics happen after
// the frame, off the carried path.
// ---------------------------------------------------------------------------
template <bool OUT>
__device__ __forceinline__ void run_frame(
    const float* __restrict__ sx, float AB,
    float BP1, float BP2, float BP3, float BP4,
    float Ba, float Bb, float Bc, float K, float IPw, int i16, int row,
    float& E0, float& E1, float& E2, float& dlp, float& xin,
    float& m1, float& m2, float& m3, float& m4, float& w0,
    float* __restrict__ ybuf)
{
    const float A = ALPHA;
    const float AA = 1.0f - A * A;
    const float A2 = A * A;
    const float R1 = -(A * A * A);
    const float R2 = R1 * R1;
    const float R4 = R2 * R2;
    const float R8 = R4 * R4;

    float xc = sx[0];
    #pragma unroll 8
    for (int k = 0; k < HOPW; ++k) {
        float xn = sx[k + 1];
        float x = xc;                                  // G pre-folded

        // stage 1 (SPTK mlsadf1), b1-rescaled, identical in all 64 lanes
        float na0 = AA * w0 + A * m1;
        float na1 = AB * m1 + A * m2;
        float na2 = AB * m2 + A * m3;
        float na3 = AB * m3 + A * m4;
        float v10 = na0 * BP1, v11 = na1 * BP2, v12 = na2 * BP3, v13 = na3 * BP4;
        float x1 = x + ((v10 - v11) + (v12 - v13));
        float y1 = ((v10 + v11) + (v12 + v13)) + x1;
        m1 = na0; m2 = na1; m3 = na2; m4 = na3; w0 = x1;

        // stage 2: blocked affine scan over the order recurrence
        float pE2 = rshr<0x111>(E2);
        float ca = fmaf(A, E0, (i16 == 0) ? dlp : pE2);
        float cb = fmaf(A, E1, E0);
        float cc = fmaf(A, E2, E1);
        float ua = ca;
        float ub = fmaf(-A, ua, cb);
        float uc = fmaf(-A, ub, cc);
        float X = uc;
        X = fmaf(R1, rshr<0x111>(X), X);
        X = fmaf(R2, rshr<0x112>(X), X);
        X = fmaf(R4, rshr<0x114>(X), X);
        X = fmaf(R8, rshr<0x118>(X), X);
        float dl = fmaf(AA, xin, A * dlp);
        float Xt = fmaf(K, dl, X);                    // true tt_{3i+2}
        float Si = rshr<0x111>(Xt);
        Si = (i16 == 0) ? dl : Si;                    // true tt_{3i-1}
        float ta = fmaf(-A, Si, ua);                  // tt_{3i}
        float tb = fmaf(A2, Si, ub);                  // tt_{3i+1}

        // P-weighted fy partial + row prefix-sum -> row totals ARE v2_r
        float fp = ta * Ba;
        fp = fmaf(tb, Bb, fp);
        fp = fmaf(Xt, Bc, fp);
        float S = fp;
        S += rshr<0x111>(S);
        S += rshr<0x112>(S);
        S += rshr<0x114>(S);
        S += rshr<0x118>(S);

        // xin for rows 1-3: previous row's total * (1/P_row), one DPP
        float xprev = rshr<0x142>(S) * IPw;

        // glue (r9-exact summation order)
        float v20 = rlane(S, 15);
        float v21 = rlane(S, 31);
        float v22 = rlane(S, 47);
        float v23 = rlane(S, 63);
        float e = v20 + v22, o = v21 + v23;
        float x2 = y1 + (e - o);
        if (OUT) {
            float y2 = (e + o) + x2;
            ybuf[k] = y2;                             // all lanes, same value (LDS)
        }

        // next-sample inputs
        xin = (row == 0) ? x2 : xprev;
        E0 = ta; E1 = tb; E2 = Xt;
        dlp = dl;
        xc = xn;
    }
}

// ---------------------------------------------------------------------------
// Kernel D: MLSA synthesis scan (block = ONE wave = one (chunk, filter)).
// P+A combine: out frames accumulate into out[] via atomicAdd after the
// frame (2 commutative adds onto 0.0 per element -> bit-exact vs ordered
// sum; out is zeroed by hipMemsetAsync before this kernel).
// ---------------------------------------------------------------------------
__global__ __launch_bounds__(64) void mlsa_kernel(
    const float* __restrict__ bcoef, const float* __restrict__ exc,
    float* __restrict__ out)
{
    __shared__ float sexc[HOPW + 2];
    __shared__ float ybuf[HOPW];

    const int tid = threadIdx.x;
    const int i16 = tid & 15;
    const int row = tid >> 4;
    const int chunk = blockIdx.x >> 3;
    const int f = blockIdx.x & 7;
    const int b = f & 3;

    const float P1 = 0.4999273f, P2 = 0.1067005f, P3 = 0.00956526f, P4 = 0.0003041358f;
    const float Pw  = (row == 0) ? P1 : (row == 1) ? P2 : (row == 2) ? P3 : P4;
    const float IPw = (row == 1) ? (1.f / P1) : (row == 2) ? (1.f / P2) : (1.f / P3);

    const float R1 = -(ALPHA * ALPHA * ALPHA);
    float K = R1;
    for (int j = 0; j < i16; ++j) K *= R1;

    float E0 = 0.f, E1 = 0.f, E2 = 0.f;
    float dlp = 0.f, xin = 0.f;
    float m1 = 0.f, m2 = 0.f, m3 = 0.f, m4 = 0.f, w0 = 0.f;

    const int outF0 = chunk * CHUNKF;

    #pragma unroll 1
    for (int i = 0; i < SERF; ++i) {
        const int ftA = outF0 - WARMF + i;

        const int ftc = (ftA < 0) ? 0 : ftA;
        const float* bp = bcoef + (f * T_FRAMES + ftc) * M1;
        const float b1 = bp[1];
        const float G  = expf(bp[0]);
        const float AA = 1.0f - ALPHA * ALPHA;
        const float AB = AA * b1;
        const float BP1 = b1 * P1, BP2 = b1 * P2, BP3 = b1 * P3, BP4 = b1 * P4;

        // stage excitation, pre-scaled by G (single wave: no barrier needed)
        for (int j = tid; j < HOPW; j += 64)
            sexc[j] = (ftA >= 0) ? exc[f * NSAMP + ftA * HOPW + j] * G : 0.f;
        if (tid == 0) sexc[HOPW] = 0.f;

        const int ja = 3 * i16 + 2;
        const float Ba = ((i16 <= 12) ? bp[ja]     : 0.f) * Pw;
        const float Bb = ((i16 <= 12) ? bp[ja + 1] : 0.f) * Pw;
        const float Bc = ((i16 <= 11) ? bp[ja + 2] : 0.f) * Pw;

        if (i >= WARMF) {
            run_frame<true>(sexc, AB, BP1, BP2, BP3, BP4, Ba, Bb, Bc, K, IPw,
                            i16, row, E0, E1, E2, dlp, xin, m1, m2, m3, m4, w0, ybuf);
            // post-frame P+A accumulate (off the carried path)
            float* op = out + b * NSAMP + ftA * HOPW;
            atomicAdd(&op[tid], ybuf[tid]);
            if (tid < HOPW - 64) atomicAdd(&op[tid + 64], ybuf[tid + 64]);
        } else {
            run_frame<false>(sexc, AB, BP1, BP2, BP3, BP4, Ba, Bb, Bc, K, IPw,
                             i16, row, E0, E1, E2, dlp, xin, m1, m2, m3, m4, w0, ybuf);
        }
    }
}

// ---------------------------------------------------------------------------
extern "C" void kernel_launch(void* const* d_in, const int* in_sizes, int n_in,
                              void* d_out, int out_size, void* d_ws, size_t ws_size,
                              hipStream_t stream) {
    const float* mceps = (const float*)d_in[0];
    const float* apdcs = (const float*)d_in[1];
    const float* f0s   = (const float*)d_in[2];
    const float* noise = (const float*)d_in[3];
    const float* Wm  = (const float*)d_in[4];
    const float* bm  = (const float*)d_in[5];
    const float* Wa  = (const float*)d_in[6];
    const float* ba  = (const float*)d_in[7];
    const float* Wf  = (const float*)d_in[8];
    const float* bf  = (const float*)d_in[9];
    const float* Wpa = (const float*)d_in[10];
    const float* bpa = (const float*)d_in[11];
    const float* Wpp = (const float*)d_in[12];
    const float* bpp = (const float*)d_in[13];
    const float* Wrp = (const float*)d_in[14];
    const float* brp = (const float*)d_in[15];
    const float* Wra = (const float*)d_in[16];
    const float* bra = (const float*)d_in[17];
    const float* Wap = (const float*)d_in[18];
    float* out = (float*)d_out;

    char* ws = (char*)d_ws;
    float* bcoef = (float*)(ws + 0);           // 256000 B
    float* exc   = (float*)(ws + 256000);      // 768000 B

    // zero the output accumulator (graph-capturable memset node)
    hipMemsetAsync(out, 0, (size_t)out_size * sizeof(float), stream);

    prep_kernel<<<dim3(EMB_BLOCKS + 8 * BPF), dim3(256), 0, stream>>>(
        mceps, apdcs, f0s, noise, Wm, bm, Wa, ba, Wf, bf,
        Wpa, bpa, Wpp, bpp, Wrp, brp, Wra, bra, Wap, bcoef, exc);

    mlsa_kernel<<<dim3(NCHUNK * 8), dim3(64), 0, stream>>>(bcoef, exc, out);
}